// Round 23
// baseline (114.584 us; speedup 1.0000x reference)
//
#include <hip/hip_runtime.h>
#include <math.h>

#define N 8192
#define H 128
#define NEV 64
#define SS 20
#define MAXD 512
#define MAXDIRTY 128
#define RPB 16
#define SPIN_GUARD (1 << 18)

#define EMB_BLOCKS (N / RPB)              // 512
#define LAM_BID    EMB_BLOCKS             // 512
#define SURV_BID0  (LAM_BID + 1)          // 513
#define PAR_BID0   (SURV_BID0 + SS)       // 533
#define GRID_ALL   (PAR_BID0 + NEV)       // 597  (<= co-residency capacity)
#define C_EMB_TARGET EMB_BLOCKS

// ---------------------------------------------------------------------------
// k_all: whole pipeline, one dispatch.
//   bids [0,512): emb role  — h_tab/z_out/d0/d1 (r22 body, pr[16*128] fix),
//                 releases c_emb.
//   bid 512:      lam; bids [513,533): survival — wait c_emb, then r22 bodies.
//   bids [533,597): par role — ballots+scan+flag run CONCURRENTLY with emb;
//                 c_emb acquire before the h_tab gather; then the proven
//                 donebits chain (r22 verbatim).
// donebits + c_emb zeroed by a 16-byte memset before this dispatch.
// ---------------------------------------------------------------------------
__global__ __launch_bounds__(512) void k_all(
    const int* __restrict__ u, const int* __restrict__ v,
    const float* __restrict__ t, const int* __restrict__ kk,
    const int* __restrict__ u_o, const int* __restrict__ v_o,
    const float* __restrict__ lastt, const float* __restrict__ emb,
    const float* __restrict__ A, const float* __restrict__ S,
    const float* __restrict__ W_S, const float* __restrict__ W_R,
    const float* __restrict__ W_t, const float* __restrict__ W_h,
    const float* __restrict__ b_h, const float* __restrict__ W_om,
    const float* __restrict__ psi, const float* __restrict__ b_om,
    float* __restrict__ h_tab, float* __restrict__ d0, float* __restrict__ d1,
    float* __restrict__ z_slot, float* __restrict__ h_slot,
    unsigned long long* __restrict__ donebits, int* __restrict__ c_emb,
    float* __restrict__ lamout, float* __restrict__ svout,
    float* __restrict__ z_out)
{
    const int bid = blockIdx.x;
    const int tid = threadIdx.x;

    __shared__ __align__(16) float z4[4 * 128];      // emb
    __shared__ float pr[16 * 128];                   // emb ([s*4+rr][c], full range)
    __shared__ int   uL[NEV], vL[NEV];               // par
    __shared__ int   nbr2[2][MAXD];
    __shared__ float nbe2[2][MAXD];
    __shared__ int   flag2[2][MAXD];
    __shared__ float rs[512];
    __shared__ float redm[512];
    __shared__ float msA[2][128];
    __shared__ int   dlsA[2][MAXDIRTY];
    __shared__ float dlqA[2][MAXDIRTY];
    __shared__ int   dcA[2], degA[2], cntA[2];
    __shared__ float sumA[2];
    __shared__ __align__(16) float hs_s[2][128];
    __shared__ __align__(16) float zz_s[2][128];
    __shared__ __align__(16) float zn_s[2][128];
    __shared__ int   zdepL[2], lastupL[2], nodeL[2];
    __shared__ float dtvL[2];
    __shared__ unsigned long long maskN[4];
    __shared__ unsigned long long maskE[2];
    __shared__ unsigned long long need_s;

    if (bid < EMB_BLOCKS) {
        // ===================== emb role (r22 body) =========================
        const int c = tid & 127;
        const int s = tid >> 7;             // 0..3
        const int r0 = bid * RPB;

        float whr[32];
#pragma unroll
        for (int i = 0; i < 32; ++i) whr[i] = W_h[c * H + s * 32 + i];
        const float bh_c = b_h[c];

        const int lane = tid & 63;
        const int wid = tid >> 6;
        const int kof = (wid >= 4) ? 256 : 0;
        const float wk_l = W_om[kof + lane]      + W_om[kof + 128 + lane];
        const float wk_h = W_om[kof + 64 + lane] + W_om[kof + 192 + lane];

        for (int b = 0; b < RPB / 4; ++b) {
            const int rbase = r0 + b * 4;
            __syncthreads();
            const float zv = emb[(size_t)rbase * H + tid];
            z4[tid] = zv;
            z_out[(size_t)rbase * H + tid] = zv;
            __syncthreads();

#pragma unroll
            for (int rr = 0; rr < 4; ++rr) {
                float a = 0.f;
#pragma unroll
                for (int i4 = 0; i4 < 8; ++i4) {
                    const float4 zz = *(const float4*)&z4[rr * 128 + s * 32 + i4 * 4];
                    a += zz.x * whr[i4 * 4] + zz.y * whr[i4 * 4 + 1] +
                         zz.z * whr[i4 * 4 + 2] + zz.w * whr[i4 * 4 + 3];
                }
                pr[(s * 4 + rr) * 128 + c] = a;
            }
            {
                const int rr = wid & 3;
                float val = z4[rr * 128 + lane] * wk_l + z4[rr * 128 + 64 + lane] * wk_h;
#pragma unroll
                for (int off = 32; off > 0; off >>= 1) val += __shfl_xor(val, off);
                if (lane == 0) {
                    if (wid < 4) d0[rbase + rr] = val;
                    else         d1[rbase + rr] = val;
                }
            }
            __syncthreads();
            {
                const int rr = s;
                const float h = pr[(0 * 4 + rr) * 128 + c] + pr[(1 * 4 + rr) * 128 + c] +
                                pr[(2 * 4 + rr) * 128 + c] + pr[(3 * 4 + rr) * 128 + c] + bh_c;
                h_tab[(size_t)(rbase + rr) * H + c] = h;
            }
        }
        __syncthreads();
        if (tid == 0) {
            __threadfence();                            // agent-scope writeback
            __hip_atomic_fetch_add(c_emb, 1, __ATOMIC_RELEASE,
                                   __HIP_MEMORY_SCOPE_AGENT);
        }
        return;
    }

    if (bid < PAR_BID0) {
        // ============ lam / survival roles (wait for emb, then r22) ========
        if (tid == 0) {
            int guard = 0;
            while (__hip_atomic_load(c_emb, __ATOMIC_ACQUIRE,
                                     __HIP_MEMORY_SCOPE_AGENT) < C_EMB_TARGET) {
                __builtin_amdgcn_s_sleep(2);
                if (++guard > SPIN_GUARD) break;
            }
        }
        __syncthreads();
        { int x = __hip_atomic_load(c_emb, __ATOMIC_ACQUIRE,
                                    __HIP_MEMORY_SCOPE_AGENT); (void)x; }

        if (bid == LAM_BID) {
            if (tid < NEV) {
                const int b = tid;
                const int kv = kk[b];
                const float* dk = kv ? d1 : d0;
                const float g = 0.5f * (dk[u[b]] + dk[v[b]]) + b_om[kv];
                const float ps = psi[kv];
                const float x = fminf(75.f, fmaxf(-75.f, g / ps));
                lamout[b] = ps * log1pf(expf(x));
            }
        } else {
            const int s = bid - SURV_BID0;
            if (tid < 64) {
                const int b = tid;
                const float p0 = psi[0], p1 = psi[1], bo0 = b_om[0], bo1 = b_om[1];
                const int vo = v_o[b * SS + s], uo = u_o[b * SS + s];
                float g, x;
                g = 0.5f * (d0[u[b]] + d0[vo]) + bo0; x = fminf(75.f, fmaxf(-75.f, g / p0));
                const float ru0 = p0 * log1pf(expf(x));
                g = 0.5f * (d1[u[b]] + d1[vo]) + bo1; x = fminf(75.f, fmaxf(-75.f, g / p1));
                const float ru1 = p1 * log1pf(expf(x));
                g = 0.5f * (d1[v[b]] + d1[uo]) + bo1; x = fminf(75.f, fmaxf(-75.f, g / p1));
                const float rv1 = p1 * log1pf(expf(x));
                float val = 2.f * (ru0 + ru1) + rv1;
#pragma unroll
                for (int off = 32; off > 0; off >>= 1) val += __shfl_xor(val, off);
                if (b == 0) svout[s] = val / (float)SS;
            }
        }
        return;
    }

    // ==================== par role (r22 + c_emb gate) ======================
    const int e = bid - PAR_BID0;
    const int r = (tid >> 7) & 1;       // compute-role row (tid<256)
    const int c = tid & 127;
    const int slot = 2 * e + r;
    const int half = tid >> 8;          // prep role: 0 -> v-row, 1 -> u-row
    const int ht = tid & 255;           // thread id within half

    if (tid < NEV)          uL[tid] = u[tid];
    else if (tid < 2 * NEV) vL[tid - NEV] = v[tid - NEV];
    if (tid < 2) { cntA[tid] = 0; dcA[tid] = 0; }
    __syncthreads();

    // ---- per-slot metadata via wave ballots (O(1)) ----
    if (tid < 256) {
        const int i  = tid >> 7;        // slot-in-event: 0 -> v-row, 1 -> u-row
        const int hj = tid & 127;       // candidate slot j
        const int lane = tid & 63;
        const int w  = tid >> 6;        // wave 0..3
        const int node = i ? uL[e] : vL[e];
        const int dtn  = i ? vL[e] : uL[e];
        const bool m1 = (((hj & 1) ? uL[hj >> 1] : vL[hj >> 1]) == node);
        const unsigned long long b1 = __ballot(m1);
        if (lane == 0) maskN[w] = b1;
        const bool m2 = (uL[lane] == dtn) || (vL[lane] == dtn);
        const unsigned long long b2 = __ballot(m2);
        if (lane == 0 && (w & 1) == 0) maskE[i] = b2;
    }
    __syncthreads();
    if (tid < 2) {
        const int i = tid;
        const int sl = 2 * e + i;
        const int dtn = i ? vL[e] : uL[e];
        nodeL[i] = i ? uL[e] : vL[e];
        const unsigned long long lo = maskN[2 * i], hi = maskN[2 * i + 1];
        auto msk = [](int n) -> unsigned long long {
            return (n >= 64) ? ~0ull : ((n <= 0) ? 0ull : ((1ull << n) - 1ull));
        };
        const unsigned long long loB = lo & msk(2 * e);
        const unsigned long long hiB = hi & msk(2 * e - 64);
        int zd = -1;
        if (hiB)      zd = 64 + (63 - __builtin_clzll(hiB));
        else if (loB) zd = 63 - __builtin_clzll(loB);
        zdepL[i] = zd;
        const unsigned long long loA = lo & ~msk(sl + 1);
        const unsigned long long hiA = hi & ~msk(sl + 1 - 64);
        lastupL[i] = ((loA | hiA) == 0ull) ? 1 : 0;
        const unsigned long long me = maskE[i] & msk(e);
        const int pt = me ? (63 - __builtin_clzll(me)) : -1;
        const float lv = (pt >= 0) ? t[pt] : lastt[dtn];
        dtvL[i] = t[e] - lv;
    }
    __syncthreads();

    // ---- fused prep: scan + flag (INDEPENDENT of emb -> overlaps it) ----
    {
        const int rowN = half ? uL[e] : vL[e];
        const size_t baseN = (size_t)rowN * N;

        // phase 1: vectorized scan, compact into LDS, sum exp(S)
        float lsum = 0.f;
        {
            const float4* A4 = (const float4*)(A + baseN);
            for (int j4 = ht; j4 < N / 4; j4 += 256) {
                const float4 a4 = A4[j4];
#pragma unroll
                for (int q = 0; q < 4; ++q) {
                    const float av = (q == 0) ? a4.x : (q == 1) ? a4.y
                                   : (q == 2) ? a4.z : a4.w;
                    if (av > 0.f) {
                        const int j = 4 * j4 + q;
                        const float ev = expf(S[baseN + j]);
                        lsum += ev;
                        const int p = atomicAdd(&cntA[half], 1);
                        if (p < MAXD) { nbr2[half][p] = j; nbe2[half][p] = ev; }
                    }
                }
            }
        }
        rs[tid] = lsum;
        __syncthreads();
        for (int off = 128; off > 0; off >>= 1) {       // per-half reduction
            if (ht < off) rs[tid] += rs[tid + off];
            __syncthreads();
        }
        if (ht == 0) { sumA[half] = rs[tid]; degA[half] = cntA[half]; }
        __syncthreads();

        const int dH = min(cntA[half], MAXD);
        const float rinvH = 1.f / (sumA[half] + 1e-7f);

        // phase 1.5: per-neighbor latest-updater slot strictly before e
        for (int j0 = ht; j0 < dH; j0 += 256) {
            const int j = nbr2[half][j0];
            int dep = -1;
            for (int s2 = 2 * e - 1; s2 >= 0; --s2) {
                const int nj = (s2 & 1) ? uL[s2 >> 1] : vL[s2 >> 1];
                if (nj == j) { dep = s2; break; }
            }
            flag2[half][j0] = dep;            // <0: static; >=0: dirty dep slot
        }
        __syncthreads();

        // ---- c_emb gate: h_tab must be complete before the gather ----
        if (tid == 0) {
            int guard = 0;
            while (__hip_atomic_load(c_emb, __ATOMIC_ACQUIRE,
                                     __HIP_MEMORY_SCOPE_AGENT) < C_EMB_TARGET) {
                __builtin_amdgcn_s_sleep(2);
                if (++guard > SPIN_GUARD) break;
            }
        }
        __syncthreads();
        { int x = __hip_atomic_load(c_emb, __ATOMIC_ACQUIRE,
                                    __HIP_MEMORY_SCOPE_AGENT); (void)x; }

        // phase 2: Mstat over static neighbors (h_tab now ready)
        {
            const int cc = ht & 127, pr2 = ht >> 7;      // 2-way per half
            float m = -INFINITY;
            for (int j0 = pr2; j0 < dH; j0 += 2) {
                if (flag2[half][j0] < 0)
                    m = fmaxf(m, nbe2[half][j0] * rinvH *
                              h_tab[(size_t)nbr2[half][j0] * H + cc]);
            }
            redm[tid] = m;
            __syncthreads();
            if (ht < 128)
                msA[half][cc] = fmaxf(redm[half * 256 + cc],
                                      redm[half * 256 + 128 + cc]);
        }

        // phase 3: dirty list (latest-updater dep slots)
        for (int j0 = ht; j0 < dH; j0 += 256) {
            const int dep = flag2[half][j0];
            if (dep >= 0) {
                const int p = atomicAdd(&dcA[half], 1);
                if (p < MAXDIRTY) { dlsA[half][p] = dep; dlqA[half][p] = nbe2[half][j0] * rinvH; }
            }
        }
        __syncthreads();
    }

    // ---- build need-mask and spin (thread 0), then per-thread acquire ----
    if (tid == 0) {
        unsigned long long need = 0ull;
        for (int rr = 0; rr < 2; ++rr) {
            const int zd = zdepL[rr];
            if (zd >= 0) need |= 1ull << (zd >> 1);
            const int dn = min(dcA[rr], MAXDIRTY);
            for (int p = 0; p < dn; ++p)
                need |= 1ull << (dlsA[rr][p] >> 1);
        }
        need_s = need;
        if (need) {
            int guard = 0;
            while ((__hip_atomic_load(donebits, __ATOMIC_ACQUIRE,
                                      __HIP_MEMORY_SCOPE_AGENT) & need) != need) {
                __builtin_amdgcn_s_sleep(2);
                if (++guard > SPIN_GUARD) break;       // safety valve
            }
        }
    }
    __syncthreads();
    if (need_s) {   // per-thread acquire: invalidate stale cache lines on this CU
        unsigned long long db = __hip_atomic_load(donebits, __ATOMIC_ACQUIRE,
                                                  __HIP_MEMORY_SCOPE_AGENT);
        (void)db;
    }

    // ---- Phase A: hs (Mstat + dirty via h_slot) and z (versioned) ----
    if (tid < 256) {
        float m = msA[r][c];
        const int dn = min(dcA[r], MAXDIRTY);
        for (int p = 0; p < dn; ++p) {
            const int ds = dlsA[r][p];
            const float q = dlqA[r][p];
            m = fmaxf(m, q * h_slot[ds * H + c]);
        }
        hs_s[r][c] = (degA[r] > 0) ? 1.f / (1.f + __expf(-m)) : 0.f;
        const int zd = zdepL[r];
        zz_s[r][c] = (zd >= 0) ? z_slot[zd * H + c]
                               : emb[(size_t)nodeL[r] * H + c];
    }
    __syncthreads();

    // ---- Phase B: g = hs.W_S[c] + z.W_R[c] + dt*W_t[c]; sigmoid ----
    if (tid < 256) {
        float g = 0.f;
        const float4* ws4 = (const float4*)(W_S + (size_t)c * H);
        const float4* wr4 = (const float4*)(W_R + (size_t)c * H);
#pragma unroll
        for (int i = 0; i < 32; ++i) {
            const float4 a = ws4[i];
            const float4 b = wr4[i];
            const float4 hh = *(const float4*)&hs_s[r][4 * i];   // LDS broadcast
            const float4 zz = *(const float4*)&zz_s[r][4 * i];
            g += hh.x * a.x + hh.y * a.y + hh.z * a.z + hh.w * a.w +
                 zz.x * b.x + zz.y * b.y + zz.z * b.z + zz.w * b.w;
        }
        g += dtvL[r] * W_t[c];
        const float zv = 1.f / (1.f + __expf(-g));
        zn_s[r][c] = zv;
        z_slot[slot * H + c] = zv;                  // versioned publish (z)
        if (lastupL[r])                             // final updater writes output
            z_out[(size_t)nodeL[r] * H + c] = zv;
    }
    __syncthreads();                                // zn_s ready for phase C

    // ---- Phase C: publish h_slot[slot] (unconditional) ----
    if (tid < 256) {
        float h = 0.f;
        const float4* wh4 = (const float4*)(W_h + (size_t)c * H);
#pragma unroll
        for (int i = 0; i < 32; ++i) {
            const float4 a = wh4[i];
            const float4 zz = *(const float4*)&zn_s[r][4 * i];
            h += zz.x * a.x + zz.y * a.y + zz.z * a.z + zz.w * a.w;
        }
        h_slot[slot * H + c] = h + b_h[c];
    }

    // ---- release (unconditional) ----
    __syncthreads();
    if (tid == 0) {
        __threadfence();                            // agent-scope write visibility
        __hip_atomic_fetch_or(donebits, 1ull << e, __ATOMIC_RELEASE,
                              __HIP_MEMORY_SCOPE_AGENT);
    }
}

// ---------------------------------------------------------------------------
extern "C" void kernel_launch(void* const* d_in, const int* in_sizes, int n_in,
                              void* d_out, int out_size, void* d_ws, size_t ws_size,
                              hipStream_t stream)
{
    const int*   u        = (const int*)d_in[0];
    const int*   v        = (const int*)d_in[1];
    const float* t        = (const float*)d_in[2];
    const int*   k        = (const int*)d_in[3];
    const int*   u_others = (const int*)d_in[4];
    const int*   v_others = (const int*)d_in[5];
    const float* A        = (const float*)d_in[6];
    const float* S        = (const float*)d_in[7];
    const float* emb      = (const float*)d_in[8];
    const float* lastt    = (const float*)d_in[9];
    const float* W_S      = (const float*)d_in[10];
    const float* W_R      = (const float*)d_in[11];
    const float* W_t      = (const float*)d_in[12];
    const float* W_h      = (const float*)d_in[13];
    const float* b_h      = (const float*)d_in[14];
    const float* psi      = (const float*)d_in[15];
    const float* W_om     = (const float*)d_in[16];
    const float* b_om     = (const float*)d_in[17];
    (void)in_sizes; (void)n_in; (void)out_size; (void)ws_size;

    // Workspace: sync block first (16-byte memset), then data.
    unsigned long long* donebits = (unsigned long long*)d_ws;    // 8
    int*   c_emb  = (int*)(donebits + 1);                        // 4 (+4 pad)
    float* h_tab  = (float*)d_ws + 4;                            // N*H
    float* d0     = h_tab + (size_t)N * H;                       // N
    float* d1     = d0 + N;                                      // N
    float* z_slot = d1 + N;                                      // 128*H
    float* h_slot = z_slot + 128 * H;                            // 128*H

    float* out    = (float*)d_out;
    float* lamout = out;            // [64]
    float* svout  = out + NEV;      // [20]
    float* z_out  = out + NEV + SS; // [N*H]

    hipMemsetAsync(d_ws, 0, 16, stream);      // donebits + c_emb
    k_all<<<GRID_ALL, 512, 0, stream>>>(u, v, t, k, u_others, v_others,
                                        lastt, emb, A, S,
                                        W_S, W_R, W_t, W_h, b_h, W_om,
                                        psi, b_om,
                                        h_tab, d0, d1, z_slot, h_slot,
                                        donebits, c_emb,
                                        lamout, svout, z_out);
}

// Round 24
// 101.408 us; speedup vs baseline: 1.1299x; 1.1299x over previous
//
#include <hip/hip_runtime.h>
#include <math.h>

#define N 8192
#define H 128
#define NEV 64
#define SS 20
#define MAXD 512
#define MAXDIRTY 128
#define RPB 8
#define SPIN_GUARD (1 << 18)

#define CPY_BLOCKS 256        // z_out copy role blocks in dispatch 2
#define PAR_GRID   (NEV + 1 + SS + CPY_BLOCKS)

// ---------------------------------------------------------------------------
// k_emb: h_tab = emb @ W_h.T + b_h ; d0/d1 rate dots. (z_out copy moved to
// dispatch 2 as independent streaming blocks.)  pr[16*128] fix retained.
// ---------------------------------------------------------------------------
__global__ __launch_bounds__(512) void k_emb(
    const float* __restrict__ emb, const float* __restrict__ W_h,
    const float* __restrict__ b_h, const float* __restrict__ W_om,
    float* __restrict__ h_tab, float* __restrict__ d0, float* __restrict__ d1,
    unsigned long long* __restrict__ donebits)
{
    const int tid = threadIdx.x;
    const int c = tid & 127;
    const int s = tid >> 7;             // 0..3
    const int r0 = blockIdx.x * RPB;

    if (blockIdx.x == 0 && tid == 0) donebits[0] = 0ull;   // for k_parls

    __shared__ __align__(16) float z4[4 * 128];
    __shared__ float pr[16 * 128];      // [s*4+rr][c], full 0..15 range

    float whr[32];
#pragma unroll
    for (int i = 0; i < 32; ++i) whr[i] = W_h[c * H + s * 32 + i];
    const float bh_c = b_h[c];

    const int lane = tid & 63;
    const int wid = tid >> 6;
    const int kof = (wid >= 4) ? 256 : 0;
    const float wk_l = W_om[kof + lane]      + W_om[kof + 128 + lane];
    const float wk_h = W_om[kof + 64 + lane] + W_om[kof + 192 + lane];

    for (int b = 0; b < RPB / 4; ++b) {
        const int rbase = r0 + b * 4;
        __syncthreads();
        z4[tid] = emb[(size_t)rbase * H + tid];
        __syncthreads();

#pragma unroll
        for (int rr = 0; rr < 4; ++rr) {
            float a = 0.f;
#pragma unroll
            for (int i4 = 0; i4 < 8; ++i4) {
                const float4 zz = *(const float4*)&z4[rr * 128 + s * 32 + i4 * 4];
                a += zz.x * whr[i4 * 4] + zz.y * whr[i4 * 4 + 1] +
                     zz.z * whr[i4 * 4 + 2] + zz.w * whr[i4 * 4 + 3];
            }
            pr[(s * 4 + rr) * 128 + c] = a;
        }
        {
            const int rr = wid & 3;
            float val = z4[rr * 128 + lane] * wk_l + z4[rr * 128 + 64 + lane] * wk_h;
#pragma unroll
            for (int off = 32; off > 0; off >>= 1) val += __shfl_xor(val, off);
            if (lane == 0) {
                if (wid < 4) d0[rbase + rr] = val;
                else         d1[rbase + rr] = val;
            }
        }
        __syncthreads();
        {
            const int rr = s;
            const float h = pr[(0 * 4 + rr) * 128 + c] + pr[(1 * 4 + rr) * 128 + c] +
                            pr[(2 * 4 + rr) * 128 + c] + pr[(3 * 4 + rr) * 128 + c] + bh_c;
            h_tab[(size_t)(rbase + rr) * H + c] = h;
        }
    }
}

// ---------------------------------------------------------------------------
// k_parls: r22 roles (par/lam/surv verbatim) + CPY_BLOCKS pure-streaming
// blocks that copy emb -> z_out (no sync participation; overlaps the par
// chain). Copy blocks write BEFORE par final-updater stores? No ordering
// needed: copy covers all rows; par's lastup store must land AFTER the
// copy's store to the same address. Guarantee: par block e waits for the
// c_cpy counter covering its 2 nodes' rows before its Phase-B store.
// Simpler + safe: copy role finishes its chunk then releases c_cpy; par
// blocks acquire c_cpy == CPY_BLOCKS before Phase B (the wait overlaps
// their scan/Mstat phases, which dominate).
// ---------------------------------------------------------------------------
__global__ __launch_bounds__(512) void k_parls(
    const int* __restrict__ u, const int* __restrict__ v,
    const float* __restrict__ t, const int* __restrict__ kk,
    const int* __restrict__ u_o, const int* __restrict__ v_o,
    const float* __restrict__ lastt, const float* __restrict__ emb,
    const float* __restrict__ A, const float* __restrict__ S,
    const float* __restrict__ h_tab,
    const float* __restrict__ W_S, const float* __restrict__ W_R,
    const float* __restrict__ W_t, const float* __restrict__ W_h,
    const float* __restrict__ b_h,
    const float* __restrict__ psi, const float* __restrict__ b_om,
    const float* __restrict__ d0, const float* __restrict__ d1,
    float* __restrict__ z_slot, float* __restrict__ h_slot,
    unsigned long long* __restrict__ donebits, int* __restrict__ c_cpy,
    float* __restrict__ lamout, float* __restrict__ svout,
    float* __restrict__ z_out)
{
    const int bid = blockIdx.x;
    const int tid = threadIdx.x;

    if (bid >= NEV + 1 + SS) {
        // ============ z_out copy role: emb -> z_out, streaming =============
        const int cb = bid - (NEV + 1 + SS);
        const size_t total = (size_t)N * H;              // 1M floats
        const size_t per = total / CPY_BLOCKS;           // 4096 floats
        const float4* src = (const float4*)(emb + cb * per);
        float4* dst = (float4*)(z_out + cb * per);
        for (size_t i = tid; i < per / 4; i += 512) dst[i] = src[i];
        __syncthreads();
        if (tid == 0) {
            __threadfence();
            __hip_atomic_fetch_add(c_cpy, 1, __ATOMIC_RELEASE,
                                   __HIP_MEMORY_SCOPE_AGENT);
        }
        return;
    }

    if (bid >= NEV) {
        // ========== lam / survival roles (prior-dispatch reads only) =======
        if (bid == NEV) {
            if (tid < NEV) {
                const int b = tid;
                const int kv = kk[b];
                const float* dk = kv ? d1 : d0;
                const float g = 0.5f * (dk[u[b]] + dk[v[b]]) + b_om[kv];
                const float ps = psi[kv];
                const float x = fminf(75.f, fmaxf(-75.f, g / ps));
                lamout[b] = ps * log1pf(expf(x));
            }
        } else {
            const int s = bid - NEV - 1;
            if (tid < 64) {
                const int b = tid;
                const float p0 = psi[0], p1 = psi[1], bo0 = b_om[0], bo1 = b_om[1];
                const int vo = v_o[b * SS + s], uo = u_o[b * SS + s];
                float g, x;
                g = 0.5f * (d0[u[b]] + d0[vo]) + bo0; x = fminf(75.f, fmaxf(-75.f, g / p0));
                const float ru0 = p0 * log1pf(expf(x));
                g = 0.5f * (d1[u[b]] + d1[vo]) + bo1; x = fminf(75.f, fmaxf(-75.f, g / p1));
                const float ru1 = p1 * log1pf(expf(x));
                g = 0.5f * (d1[v[b]] + d1[uo]) + bo1; x = fminf(75.f, fmaxf(-75.f, g / p1));
                const float rv1 = p1 * log1pf(expf(x));
                float val = 2.f * (ru0 + ru1) + rv1;
#pragma unroll
                for (int off = 32; off > 0; off >>= 1) val += __shfl_xor(val, off);
                if (b == 0) svout[s] = val / (float)SS;
            }
        }
        return;
    }

    // ==================== par role with fused dual-slot prep ===============
    const int e = bid;
    const int r = (tid >> 7) & 1;       // compute-role row (tid<256)
    const int c = tid & 127;
    const int slot = 2 * e + r;
    const int half = tid >> 8;          // prep role: 0 -> v-row, 1 -> u-row
    const int ht = tid & 255;           // thread id within half

    __shared__ int   uL[NEV], vL[NEV];
    __shared__ int   nbr2[2][MAXD];
    __shared__ float nbe2[2][MAXD];
    __shared__ int   flag2[2][MAXD];
    __shared__ float rs[512];
    __shared__ float redm[512];
    __shared__ float msA[2][128];
    __shared__ int   dlsA[2][MAXDIRTY];
    __shared__ float dlqA[2][MAXDIRTY];
    __shared__ int   dcA[2], degA[2], cntA[2];
    __shared__ float sumA[2];
    __shared__ __align__(16) float hs_s[2][128];
    __shared__ __align__(16) float zz_s[2][128];
    __shared__ __align__(16) float zn_s[2][128];
    __shared__ int   zdepL[2], lastupL[2], nodeL[2];
    __shared__ float dtvL[2];
    __shared__ unsigned long long maskN[4];
    __shared__ unsigned long long maskE[2];
    __shared__ unsigned long long need_s;

    if (tid < NEV)          uL[tid] = u[tid];
    else if (tid < 2 * NEV) vL[tid - NEV] = v[tid - NEV];
    if (tid < 2) { cntA[tid] = 0; dcA[tid] = 0; }
    __syncthreads();

    // ---- per-slot metadata via wave ballots (O(1)) ----
    if (tid < 256) {
        const int i  = tid >> 7;        // slot-in-event: 0 -> v-row, 1 -> u-row
        const int hj = tid & 127;       // candidate slot j
        const int lane = tid & 63;
        const int w  = tid >> 6;        // wave 0..3
        const int node = i ? uL[e] : vL[e];
        const int dtn  = i ? vL[e] : uL[e];
        const bool m1 = (((hj & 1) ? uL[hj >> 1] : vL[hj >> 1]) == node);
        const unsigned long long b1 = __ballot(m1);
        if (lane == 0) maskN[w] = b1;
        const bool m2 = (uL[lane] == dtn) || (vL[lane] == dtn);
        const unsigned long long b2 = __ballot(m2);
        if (lane == 0 && (w & 1) == 0) maskE[i] = b2;
    }
    __syncthreads();
    if (tid < 2) {
        const int i = tid;
        const int sl = 2 * e + i;
        const int dtn = i ? vL[e] : uL[e];
        nodeL[i] = i ? uL[e] : vL[e];
        const unsigned long long lo = maskN[2 * i], hi = maskN[2 * i + 1];
        auto msk = [](int n) -> unsigned long long {
            return (n >= 64) ? ~0ull : ((n <= 0) ? 0ull : ((1ull << n) - 1ull));
        };
        const unsigned long long loB = lo & msk(2 * e);
        const unsigned long long hiB = hi & msk(2 * e - 64);
        int zd = -1;
        if (hiB)      zd = 64 + (63 - __builtin_clzll(hiB));
        else if (loB) zd = 63 - __builtin_clzll(loB);
        zdepL[i] = zd;
        const unsigned long long loA = lo & ~msk(sl + 1);
        const unsigned long long hiA = hi & ~msk(sl + 1 - 64);
        lastupL[i] = ((loA | hiA) == 0ull) ? 1 : 0;
        const unsigned long long me = maskE[i] & msk(e);
        const int pt = me ? (63 - __builtin_clzll(me)) : -1;
        const float lv = (pt >= 0) ? t[pt] : lastt[dtn];
        dtvL[i] = t[e] - lv;
    }
    __syncthreads();

    // ---- fused prep: each half scans its own adjacency row ----
    {
        const int rowN = half ? uL[e] : vL[e];
        const size_t baseN = (size_t)rowN * N;

        // phase 1: vectorized scan, compact into LDS, sum exp(S)
        float lsum = 0.f;
        {
            const float4* A4 = (const float4*)(A + baseN);
            for (int j4 = ht; j4 < N / 4; j4 += 256) {
                const float4 a4 = A4[j4];
#pragma unroll
                for (int q = 0; q < 4; ++q) {
                    const float av = (q == 0) ? a4.x : (q == 1) ? a4.y
                                   : (q == 2) ? a4.z : a4.w;
                    if (av > 0.f) {
                        const int j = 4 * j4 + q;
                        const float ev = expf(S[baseN + j]);
                        lsum += ev;
                        const int p = atomicAdd(&cntA[half], 1);
                        if (p < MAXD) { nbr2[half][p] = j; nbe2[half][p] = ev; }
                    }
                }
            }
        }
        rs[tid] = lsum;
        __syncthreads();
        for (int off = 128; off > 0; off >>= 1) {       // per-half reduction
            if (ht < off) rs[tid] += rs[tid + off];
            __syncthreads();
        }
        if (ht == 0) { sumA[half] = rs[tid]; degA[half] = cntA[half]; }
        __syncthreads();

        const int dH = min(cntA[half], MAXD);
        const float rinvH = 1.f / (sumA[half] + 1e-7f);

        // phase 1.5: per-neighbor latest-updater slot strictly before e
        for (int j0 = ht; j0 < dH; j0 += 256) {
            const int j = nbr2[half][j0];
            int dep = -1;
            for (int s2 = 2 * e - 1; s2 >= 0; --s2) {
                const int nj = (s2 & 1) ? uL[s2 >> 1] : vL[s2 >> 1];
                if (nj == j) { dep = s2; break; }
            }
            flag2[half][j0] = dep;            // <0: static; >=0: dirty dep slot
        }
        __syncthreads();

        // phase 2: Mstat over static neighbors (h_tab, prior dispatch)
        {
            const int cc = ht & 127, pr2 = ht >> 7;      // 2-way per half
            float m = -INFINITY;
            for (int j0 = pr2; j0 < dH; j0 += 2) {
                if (flag2[half][j0] < 0)
                    m = fmaxf(m, nbe2[half][j0] * rinvH *
                              h_tab[(size_t)nbr2[half][j0] * H + cc]);
            }
            redm[tid] = m;
            __syncthreads();
            if (ht < 128)
                msA[half][cc] = fmaxf(redm[half * 256 + cc],
                                      redm[half * 256 + 128 + cc]);
        }

        // phase 3: dirty list (latest-updater dep slots)
        for (int j0 = ht; j0 < dH; j0 += 256) {
            const int dep = flag2[half][j0];
            if (dep >= 0) {
                const int p = atomicAdd(&dcA[half], 1);
                if (p < MAXDIRTY) { dlsA[half][p] = dep; dlqA[half][p] = nbe2[half][j0] * rinvH; }
            }
        }
        __syncthreads();
    }

    // ---- wait for copy role (z_out base coverage) — overlapped by prep ----
    if (tid == 0) {
        int guard = 0;
        while (__hip_atomic_load(c_cpy, __ATOMIC_ACQUIRE,
                                 __HIP_MEMORY_SCOPE_AGENT) < CPY_BLOCKS) {
            __builtin_amdgcn_s_sleep(2);
            if (++guard > SPIN_GUARD) break;
        }
    }
    __syncthreads();
    { int x = __hip_atomic_load(c_cpy, __ATOMIC_ACQUIRE,
                                __HIP_MEMORY_SCOPE_AGENT); (void)x; }

    // ---- build need-mask and spin (thread 0), then per-thread acquire ----
    if (tid == 0) {
        unsigned long long need = 0ull;
        for (int rr = 0; rr < 2; ++rr) {
            const int zd = zdepL[rr];
            if (zd >= 0) need |= 1ull << (zd >> 1);
            const int dn = min(dcA[rr], MAXDIRTY);
            for (int p = 0; p < dn; ++p)
                need |= 1ull << (dlsA[rr][p] >> 1);
        }
        need_s = need;
        if (need) {
            int guard = 0;
            while ((__hip_atomic_load(donebits, __ATOMIC_ACQUIRE,
                                      __HIP_MEMORY_SCOPE_AGENT) & need) != need) {
                __builtin_amdgcn_s_sleep(2);
                if (++guard > SPIN_GUARD) break;       // safety valve
            }
        }
    }
    __syncthreads();
    if (need_s) {   // per-thread acquire: invalidate stale cache lines on this CU
        unsigned long long db = __hip_atomic_load(donebits, __ATOMIC_ACQUIRE,
                                                  __HIP_MEMORY_SCOPE_AGENT);
        (void)db;
    }

    // ---- Phase A: hs (Mstat + dirty via h_slot) and z (versioned) ----
    if (tid < 256) {
        float m = msA[r][c];
        const int dn = min(dcA[r], MAXDIRTY);
        for (int p = 0; p < dn; ++p) {
            const int ds = dlsA[r][p];
            const float q = dlqA[r][p];
            m = fmaxf(m, q * h_slot[ds * H + c]);
        }
        hs_s[r][c] = (degA[r] > 0) ? 1.f / (1.f + __expf(-m)) : 0.f;
        const int zd = zdepL[r];
        zz_s[r][c] = (zd >= 0) ? z_slot[zd * H + c]
                               : emb[(size_t)nodeL[r] * H + c];
    }
    __syncthreads();

    // ---- Phase B: g = hs.W_S[c] + z.W_R[c] + dt*W_t[c]; sigmoid ----
    if (tid < 256) {
        float g = 0.f;
        const float4* ws4 = (const float4*)(W_S + (size_t)c * H);
        const float4* wr4 = (const float4*)(W_R + (size_t)c * H);
#pragma unroll
        for (int i = 0; i < 32; ++i) {
            const float4 a = ws4[i];
            const float4 b = wr4[i];
            const float4 hh = *(const float4*)&hs_s[r][4 * i];   // LDS broadcast
            const float4 zz = *(const float4*)&zz_s[r][4 * i];
            g += hh.x * a.x + hh.y * a.y + hh.z * a.z + hh.w * a.w +
                 zz.x * b.x + zz.y * b.y + zz.z * b.z + zz.w * b.w;
        }
        g += dtvL[r] * W_t[c];
        const float zv = 1.f / (1.f + __expf(-g));
        zn_s[r][c] = zv;
        z_slot[slot * H + c] = zv;                  // versioned publish (z)
        if (lastupL[r])                             // final updater writes output
            z_out[(size_t)nodeL[r] * H + c] = zv;
    }
    __syncthreads();                                // zn_s ready for phase C

    // ---- Phase C: publish h_slot[slot] (unconditional) ----
    if (tid < 256) {
        float h = 0.f;
        const float4* wh4 = (const float4*)(W_h + (size_t)c * H);
#pragma unroll
        for (int i = 0; i < 32; ++i) {
            const float4 a = wh4[i];
            const float4 zz = *(const float4*)&zn_s[r][4 * i];
            h += zz.x * a.x + zz.y * a.y + zz.z * a.z + zz.w * a.w;
        }
        h_slot[slot * H + c] = h + b_h[c];
    }

    // ---- release (unconditional) ----
    __syncthreads();
    if (tid == 0) {
        __threadfence();                            // agent-scope write visibility
        __hip_atomic_fetch_or(donebits, 1ull << e, __ATOMIC_RELEASE,
                              __HIP_MEMORY_SCOPE_AGENT);
    }
}

// ---------------------------------------------------------------------------
extern "C" void kernel_launch(void* const* d_in, const int* in_sizes, int n_in,
                              void* d_out, int out_size, void* d_ws, size_t ws_size,
                              hipStream_t stream)
{
    const int*   u        = (const int*)d_in[0];
    const int*   v        = (const int*)d_in[1];
    const float* t        = (const float*)d_in[2];
    const int*   k        = (const int*)d_in[3];
    const int*   u_others = (const int*)d_in[4];
    const int*   v_others = (const int*)d_in[5];
    const float* A        = (const float*)d_in[6];
    const float* S        = (const float*)d_in[7];
    const float* emb      = (const float*)d_in[8];
    const float* lastt    = (const float*)d_in[9];
    const float* W_S      = (const float*)d_in[10];
    const float* W_R      = (const float*)d_in[11];
    const float* W_t      = (const float*)d_in[12];
    const float* W_h      = (const float*)d_in[13];
    const float* b_h      = (const float*)d_in[14];
    const float* psi      = (const float*)d_in[15];
    const float* W_om     = (const float*)d_in[16];
    const float* b_om     = (const float*)d_in[17];
    (void)in_sizes; (void)n_in; (void)out_size; (void)ws_size;

    // Workspace: sync block first, then data. c_cpy zeroed by k_emb? No —
    // memset both counters here (16 bytes, negligible).
    unsigned long long* donebits = (unsigned long long*)d_ws;    // 8
    int*   c_cpy  = (int*)(donebits + 1);                        // 4 (+4 pad)
    float* h_tab  = (float*)d_ws + 4;                            // N*H
    float* d0     = h_tab + (size_t)N * H;                       // N
    float* d1     = d0 + N;                                      // N
    float* z_slot = d1 + N;                                      // 128*H
    float* h_slot = z_slot + 128 * H;                            // 128*H

    float* out    = (float*)d_out;
    float* lamout = out;            // [64]
    float* svout  = out + NEV;      // [20]
    float* z_out  = out + NEV + SS; // [N*H]

    hipMemsetAsync(d_ws, 0, 16, stream);      // donebits + c_cpy
    k_emb<<<N / RPB, 512, 0, stream>>>(emb, W_h, b_h, W_om, h_tab, d0, d1, donebits);
    k_parls<<<PAR_GRID, 512, 0, stream>>>(u, v, t, k, u_others, v_others,
                                          lastt, emb, A, S, h_tab,
                                          W_S, W_R, W_t, W_h, b_h,
                                          psi, b_om, d0, d1,
                                          z_slot, h_slot, donebits, c_cpy,
                                          lamout, svout, z_out);
}

// Round 25
// 86.994 us; speedup vs baseline: 1.3171x; 1.1657x over previous
//
#include <hip/hip_runtime.h>
#include <math.h>

#define N 8192
#define H 128
#define NEV 64
#define SS 20
#define MAXD 512
#define MAXDIRTY 128
#define RPB 8
#define SPIN_GUARD (1 << 18)

// ---------------------------------------------------------------------------
// k_emb: h_tab = emb @ W_h.T + b_h ; z_out = emb copy ; d0/d1 rate dots.
// pr is [16][128] — indices (s*4+rr) span 0..15 (the r1-r21 latent OOB fix).
// ---------------------------------------------------------------------------
__global__ __launch_bounds__(512) void k_emb(
    const float* __restrict__ emb, const float* __restrict__ W_h,
    const float* __restrict__ b_h, const float* __restrict__ W_om,
    float* __restrict__ h_tab, float* __restrict__ z_out,
    float* __restrict__ d0, float* __restrict__ d1,
    unsigned long long* __restrict__ donebits)
{
    const int tid = threadIdx.x;
    const int c = tid & 127;
    const int s = tid >> 7;             // 0..3
    const int r0 = blockIdx.x * RPB;

    if (blockIdx.x == 0 && tid == 0) donebits[0] = 0ull;   // for k_parls

    __shared__ __align__(16) float z4[4 * 128];
    __shared__ float pr[16 * 128];      // [s*4+rr][c], s,rr in 0..3

    float whr[32];
#pragma unroll
    for (int i = 0; i < 32; ++i) whr[i] = W_h[c * H + s * 32 + i];
    const float bh_c = b_h[c];

    const int lane = tid & 63;
    const int wid = tid >> 6;
    const int kof = (wid >= 4) ? 256 : 0;
    const float wk_l = W_om[kof + lane]      + W_om[kof + 128 + lane];
    const float wk_h = W_om[kof + 64 + lane] + W_om[kof + 192 + lane];

    for (int b = 0; b < RPB / 4; ++b) {
        const int rbase = r0 + b * 4;
        __syncthreads();
        const float zv = emb[(size_t)rbase * H + tid];
        z4[tid] = zv;
        z_out[(size_t)rbase * H + tid] = zv;
        __syncthreads();

#pragma unroll
        for (int rr = 0; rr < 4; ++rr) {
            float a = 0.f;
#pragma unroll
            for (int i4 = 0; i4 < 8; ++i4) {
                const float4 zz = *(const float4*)&z4[rr * 128 + s * 32 + i4 * 4];
                a += zz.x * whr[i4 * 4] + zz.y * whr[i4 * 4 + 1] +
                     zz.z * whr[i4 * 4 + 2] + zz.w * whr[i4 * 4 + 3];
            }
            pr[(s * 4 + rr) * 128 + c] = a;
        }
        {
            const int rr = wid & 3;
            float val = z4[rr * 128 + lane] * wk_l + z4[rr * 128 + 64 + lane] * wk_h;
#pragma unroll
            for (int off = 32; off > 0; off >>= 1) val += __shfl_xor(val, off);
            if (lane == 0) {
                if (wid < 4) d0[rbase + rr] = val;
                else         d1[rbase + rr] = val;
            }
        }
        __syncthreads();
        {
            const int rr = s;
            const float h = pr[(0 * 4 + rr) * 128 + c] + pr[(1 * 4 + rr) * 128 + c] +
                            pr[(2 * 4 + rr) * 128 + c] + pr[(3 * 4 + rr) * 128 + c] + bh_c;
            h_tab[(size_t)(rbase + rr) * H + c] = h;
        }
    }
}

// ---------------------------------------------------------------------------
// k_parls: blocks 0..63 = par role (ballot metadata + fused dual-slot prep +
// donebits chain); block 64 = lam; 65..84 = survival.
// ---------------------------------------------------------------------------
__global__ __launch_bounds__(512) void k_parls(
    const int* __restrict__ u, const int* __restrict__ v,
    const float* __restrict__ t, const int* __restrict__ kk,
    const int* __restrict__ u_o, const int* __restrict__ v_o,
    const float* __restrict__ lastt, const float* __restrict__ emb,
    const float* __restrict__ A, const float* __restrict__ S,
    const float* __restrict__ h_tab,
    const float* __restrict__ W_S, const float* __restrict__ W_R,
    const float* __restrict__ W_t, const float* __restrict__ W_h,
    const float* __restrict__ b_h,
    const float* __restrict__ psi, const float* __restrict__ b_om,
    const float* __restrict__ d0, const float* __restrict__ d1,
    float* __restrict__ z_slot, float* __restrict__ h_slot,
    unsigned long long* __restrict__ donebits,
    float* __restrict__ lamout, float* __restrict__ svout,
    float* __restrict__ z_out)
{
    const int bid = blockIdx.x;
    const int tid = threadIdx.x;

    if (bid >= NEV) {
        // ========== lam / survival roles (prior-dispatch reads only) =======
        if (bid == NEV) {
            if (tid < NEV) {
                const int b = tid;
                const int kv = kk[b];
                const float* dk = kv ? d1 : d0;
                const float g = 0.5f * (dk[u[b]] + dk[v[b]]) + b_om[kv];
                const float ps = psi[kv];
                const float x = fminf(75.f, fmaxf(-75.f, g / ps));
                lamout[b] = ps * log1pf(expf(x));
            }
        } else {
            const int s = bid - NEV - 1;
            if (tid < 64) {
                const int b = tid;
                const float p0 = psi[0], p1 = psi[1], bo0 = b_om[0], bo1 = b_om[1];
                const int vo = v_o[b * SS + s], uo = u_o[b * SS + s];
                float g, x;
                g = 0.5f * (d0[u[b]] + d0[vo]) + bo0; x = fminf(75.f, fmaxf(-75.f, g / p0));
                const float ru0 = p0 * log1pf(expf(x));
                g = 0.5f * (d1[u[b]] + d1[vo]) + bo1; x = fminf(75.f, fmaxf(-75.f, g / p1));
                const float ru1 = p1 * log1pf(expf(x));
                g = 0.5f * (d1[v[b]] + d1[uo]) + bo1; x = fminf(75.f, fmaxf(-75.f, g / p1));
                const float rv1 = p1 * log1pf(expf(x));
                float val = 2.f * (ru0 + ru1) + rv1;
#pragma unroll
                for (int off = 32; off > 0; off >>= 1) val += __shfl_xor(val, off);
                if (b == 0) svout[s] = val / (float)SS;
            }
        }
        return;
    }

    // ==================== par role with fused dual-slot prep ===============
    const int e = bid;
    const int r = (tid >> 7) & 1;       // compute-role row (tid<256)
    const int c = tid & 127;
    const int slot = 2 * e + r;
    const int half = tid >> 8;          // prep role: 0 -> v-row, 1 -> u-row
    const int ht = tid & 255;           // thread id within half

    __shared__ int   uL[NEV], vL[NEV];
    __shared__ int   nbr2[2][MAXD];
    __shared__ float nbe2[2][MAXD];
    __shared__ int   flag2[2][MAXD];
    __shared__ float rs[512];
    __shared__ float redm[512];
    __shared__ float msA[2][128];
    __shared__ int   dlsA[2][MAXDIRTY];
    __shared__ float dlqA[2][MAXDIRTY];
    __shared__ int   dcA[2], degA[2], cntA[2];
    __shared__ float sumA[2];
    __shared__ __align__(16) float hs_s[2][128];
    __shared__ __align__(16) float zz_s[2][128];
    __shared__ __align__(16) float zn_s[2][128];
    __shared__ int   zdepL[2], lastupL[2], nodeL[2];
    __shared__ float dtvL[2];
    __shared__ unsigned long long maskN[4];
    __shared__ unsigned long long maskE[2];
    __shared__ unsigned long long need_s;

    if (tid < NEV)          uL[tid] = u[tid];
    else if (tid < 2 * NEV) vL[tid - NEV] = v[tid - NEV];
    if (tid < 2) { cntA[tid] = 0; dcA[tid] = 0; }
    __syncthreads();

    // ---- per-slot metadata via wave ballots (O(1)) ----
    if (tid < 256) {
        const int i  = tid >> 7;        // slot-in-event: 0 -> v-row, 1 -> u-row
        const int hj = tid & 127;       // candidate slot j
        const int lane = tid & 63;
        const int w  = tid >> 6;        // wave 0..3
        const int node = i ? uL[e] : vL[e];
        const int dtn  = i ? vL[e] : uL[e];
        const bool m1 = (((hj & 1) ? uL[hj >> 1] : vL[hj >> 1]) == node);
        const unsigned long long b1 = __ballot(m1);
        if (lane == 0) maskN[w] = b1;
        const bool m2 = (uL[lane] == dtn) || (vL[lane] == dtn);
        const unsigned long long b2 = __ballot(m2);
        if (lane == 0 && (w & 1) == 0) maskE[i] = b2;
    }
    __syncthreads();
    if (tid < 2) {
        const int i = tid;
        const int sl = 2 * e + i;
        const int dtn = i ? vL[e] : uL[e];
        nodeL[i] = i ? uL[e] : vL[e];
        const unsigned long long lo = maskN[2 * i], hi = maskN[2 * i + 1];
        auto msk = [](int n) -> unsigned long long {
            return (n >= 64) ? ~0ull : ((n <= 0) ? 0ull : ((1ull << n) - 1ull));
        };
        const unsigned long long loB = lo & msk(2 * e);
        const unsigned long long hiB = hi & msk(2 * e - 64);
        int zd = -1;
        if (hiB)      zd = 64 + (63 - __builtin_clzll(hiB));
        else if (loB) zd = 63 - __builtin_clzll(loB);
        zdepL[i] = zd;
        const unsigned long long loA = lo & ~msk(sl + 1);
        const unsigned long long hiA = hi & ~msk(sl + 1 - 64);
        lastupL[i] = ((loA | hiA) == 0ull) ? 1 : 0;
        const unsigned long long me = maskE[i] & msk(e);
        const int pt = me ? (63 - __builtin_clzll(me)) : -1;
        const float lv = (pt >= 0) ? t[pt] : lastt[dtn];
        dtvL[i] = t[e] - lv;
    }
    __syncthreads();

    // ---- fused prep: each half scans its own adjacency row ----
    {
        const int rowN = half ? uL[e] : vL[e];
        const size_t baseN = (size_t)rowN * N;

        // phase 1: vectorized scan, compact into LDS, sum exp(S)
        float lsum = 0.f;
        {
            const float4* A4 = (const float4*)(A + baseN);
            for (int j4 = ht; j4 < N / 4; j4 += 256) {
                const float4 a4 = A4[j4];
#pragma unroll
                for (int q = 0; q < 4; ++q) {
                    const float av = (q == 0) ? a4.x : (q == 1) ? a4.y
                                   : (q == 2) ? a4.z : a4.w;
                    if (av > 0.f) {
                        const int j = 4 * j4 + q;
                        const float ev = expf(S[baseN + j]);
                        lsum += ev;
                        const int p = atomicAdd(&cntA[half], 1);
                        if (p < MAXD) { nbr2[half][p] = j; nbe2[half][p] = ev; }
                    }
                }
            }
        }
        rs[tid] = lsum;
        __syncthreads();
        for (int off = 128; off > 0; off >>= 1) {       // per-half reduction
            if (ht < off) rs[tid] += rs[tid + off];
            __syncthreads();
        }
        if (ht == 0) { sumA[half] = rs[tid]; degA[half] = cntA[half]; }
        __syncthreads();

        const int dH = min(cntA[half], MAXD);
        const float rinvH = 1.f / (sumA[half] + 1e-7f);

        // phase 1.5: per-neighbor latest-updater slot strictly before e
        for (int j0 = ht; j0 < dH; j0 += 256) {
            const int j = nbr2[half][j0];
            int dep = -1;
            for (int s2 = 2 * e - 1; s2 >= 0; --s2) {
                const int nj = (s2 & 1) ? uL[s2 >> 1] : vL[s2 >> 1];
                if (nj == j) { dep = s2; break; }
            }
            flag2[half][j0] = dep;            // <0: static; >=0: dirty dep slot
        }
        __syncthreads();

        // phase 2: Mstat over static neighbors (h_tab, prior dispatch)
        {
            const int cc = ht & 127, pr2 = ht >> 7;      // 2-way per half
            float m = -INFINITY;
            for (int j0 = pr2; j0 < dH; j0 += 2) {
                if (flag2[half][j0] < 0)
                    m = fmaxf(m, nbe2[half][j0] * rinvH *
                              h_tab[(size_t)nbr2[half][j0] * H + cc]);
            }
            redm[tid] = m;
            __syncthreads();
            if (ht < 128)
                msA[half][cc] = fmaxf(redm[half * 256 + cc],
                                      redm[half * 256 + 128 + cc]);
        }

        // phase 3: dirty list (latest-updater dep slots)
        for (int j0 = ht; j0 < dH; j0 += 256) {
            const int dep = flag2[half][j0];
            if (dep >= 0) {
                const int p = atomicAdd(&dcA[half], 1);
                if (p < MAXDIRTY) { dlsA[half][p] = dep; dlqA[half][p] = nbe2[half][j0] * rinvH; }
            }
        }
        __syncthreads();
    }

    // ---- build need-mask and spin (thread 0), then per-thread acquire ----
    if (tid == 0) {
        unsigned long long need = 0ull;
        for (int rr = 0; rr < 2; ++rr) {
            const int zd = zdepL[rr];
            if (zd >= 0) need |= 1ull << (zd >> 1);
            const int dn = min(dcA[rr], MAXDIRTY);
            for (int p = 0; p < dn; ++p)
                need |= 1ull << (dlsA[rr][p] >> 1);
        }
        need_s = need;
        if (need) {
            int guard = 0;
            while ((__hip_atomic_load(donebits, __ATOMIC_ACQUIRE,
                                      __HIP_MEMORY_SCOPE_AGENT) & need) != need) {
                __builtin_amdgcn_s_sleep(2);
                if (++guard > SPIN_GUARD) break;       // safety valve
            }
        }
    }
    __syncthreads();
    if (need_s) {   // per-thread acquire: invalidate stale cache lines on this CU
        unsigned long long db = __hip_atomic_load(donebits, __ATOMIC_ACQUIRE,
                                                  __HIP_MEMORY_SCOPE_AGENT);
        (void)db;
    }

    // ---- Phase A: hs (Mstat + dirty via h_slot) and z (versioned) ----
    if (tid < 256) {
        float m = msA[r][c];
        const int dn = min(dcA[r], MAXDIRTY);
        for (int p = 0; p < dn; ++p) {
            const int ds = dlsA[r][p];
            const float q = dlqA[r][p];
            m = fmaxf(m, q * h_slot[ds * H + c]);
        }
        hs_s[r][c] = (degA[r] > 0) ? 1.f / (1.f + __expf(-m)) : 0.f;
        const int zd = zdepL[r];
        zz_s[r][c] = (zd >= 0) ? z_slot[zd * H + c]
                               : emb[(size_t)nodeL[r] * H + c];
    }
    __syncthreads();

    // ---- Phase B: g = hs.W_S[c] + z.W_R[c] + dt*W_t[c]; sigmoid ----
    if (tid < 256) {
        float g = 0.f;
        const float4* ws4 = (const float4*)(W_S + (size_t)c * H);
        const float4* wr4 = (const float4*)(W_R + (size_t)c * H);
#pragma unroll
        for (int i = 0; i < 32; ++i) {
            const float4 a = ws4[i];
            const float4 b = wr4[i];
            const float4 hh = *(const float4*)&hs_s[r][4 * i];   // LDS broadcast
            const float4 zz = *(const float4*)&zz_s[r][4 * i];
            g += hh.x * a.x + hh.y * a.y + hh.z * a.z + hh.w * a.w +
                 zz.x * b.x + zz.y * b.y + zz.z * b.z + zz.w * b.w;
        }
        g += dtvL[r] * W_t[c];
        const float zv = 1.f / (1.f + __expf(-g));
        zn_s[r][c] = zv;
        z_slot[slot * H + c] = zv;                  // versioned publish (z)
        if (lastupL[r])                             // final updater writes output
            z_out[(size_t)nodeL[r] * H + c] = zv;
    }
    __syncthreads();                                // zn_s ready for phase C

    // ---- Phase C: publish h_slot[slot] (unconditional) ----
    if (tid < 256) {
        float h = 0.f;
        const float4* wh4 = (const float4*)(W_h + (size_t)c * H);
#pragma unroll
        for (int i = 0; i < 32; ++i) {
            const float4 a = wh4[i];
            const float4 zz = *(const float4*)&zn_s[r][4 * i];
            h += zz.x * a.x + zz.y * a.y + zz.z * a.z + zz.w * a.w;
        }
        h_slot[slot * H + c] = h + b_h[c];
    }

    // ---- release (unconditional) ----
    __syncthreads();
    if (tid == 0) {
        __threadfence();                            // agent-scope write visibility
        __hip_atomic_fetch_or(donebits, 1ull << e, __ATOMIC_RELEASE,
                              __HIP_MEMORY_SCOPE_AGENT);
    }
}

// ---------------------------------------------------------------------------
extern "C" void kernel_launch(void* const* d_in, const int* in_sizes, int n_in,
                              void* d_out, int out_size, void* d_ws, size_t ws_size,
                              hipStream_t stream)
{
    const int*   u        = (const int*)d_in[0];
    const int*   v        = (const int*)d_in[1];
    const float* t        = (const float*)d_in[2];
    const int*   k        = (const int*)d_in[3];
    const int*   u_others = (const int*)d_in[4];
    const int*   v_others = (const int*)d_in[5];
    const float* A        = (const float*)d_in[6];
    const float* S        = (const float*)d_in[7];
    const float* emb      = (const float*)d_in[8];
    const float* lastt    = (const float*)d_in[9];
    const float* W_S      = (const float*)d_in[10];
    const float* W_R      = (const float*)d_in[11];
    const float* W_t      = (const float*)d_in[12];
    const float* W_h      = (const float*)d_in[13];
    const float* b_h      = (const float*)d_in[14];
    const float* psi      = (const float*)d_in[15];
    const float* W_om     = (const float*)d_in[16];
    const float* b_om     = (const float*)d_in[17];
    (void)in_sizes; (void)n_in; (void)out_size; (void)ws_size;

    // Workspace layout as r22.
    float* wsf    = (float*)d_ws;
    float* h_tab  = wsf;                            // N*H
    float* d0     = h_tab + (size_t)N * H;          // N
    float* d1     = d0 + N;                         // N
    float* Mstat  = d1 + N;                         // 128*H (dead)
    float* dl_q   = Mstat + 128 * H;                // 128*MAXDIRTY (dead)
    float* z_slot = dl_q + 128 * MAXDIRTY;          // 128*H
    float* h_slot = z_slot + 128 * H;               // 128*H
    int*   deg    = (int*)(h_slot + 128 * H);       // 128 (dead)
    int*   dcnt   = deg + 128;                      // 128 (dead)
    int*   dl_s   = dcnt + 128;                     // 128*MAXDIRTY (dead)
    unsigned long long* donebits = (unsigned long long*)(dl_s + 128 * MAXDIRTY);

    float* out    = (float*)d_out;
    float* lamout = out;            // [64]
    float* svout  = out + NEV;      // [20]
    float* z_out  = out + NEV + SS; // [N*H]

    k_emb<<<N / RPB, 512, 0, stream>>>(emb, W_h, b_h, W_om, h_tab, z_out,
                                       d0, d1, donebits);
    k_parls<<<NEV + 1 + SS, 512, 0, stream>>>(u, v, t, k, u_others, v_others,
                                              lastt, emb, A, S, h_tab,
                                              W_S, W_R, W_t, W_h, b_h,
                                              psi, b_om, d0, d1,
                                              z_slot, h_slot, donebits,
                                              lamout, svout, z_out);
}